// Round 7
// baseline (87.565 us; speedup 1.0000x reference)
//
#include <hip/hip_runtime.h>

#define IN_F 8192
#define OUT_F 8192
#define BATCH 64
#define TQ 64                   // output columns per tile
#define NTILE (OUT_F / TQ)      // 128 tiles
#define ROWS 32                 // batch rows per block (grid.y = 2)
#define PASS 2048               // feature-scan pass size; list cap == PASS => no overflow
#define CH 64                   // entries per chunk

// ---------------- Kernel 1: transpose x [64, 8192] -> xT [8192, 64] ----------------
__global__ __launch_bounds__(256) void transpose_x_kern(const float* __restrict__ x,
                                                        float* __restrict__ xT) {
    __shared__ float tile[64][65];   // +1 pad: conflict-free
    const int i0 = blockIdx.x * 64;
    const int tid = threadIdx.x;
#pragma unroll
    for (int u = tid; u < 64 * 64; u += 256) {
        const int b = u >> 6;
        const int i = u & 63;          // fastest -> coalesced reads
        tile[i][b] = x[b * IN_F + i0 + i];
    }
    __syncthreads();
#pragma unroll
    for (int u = tid; u < 64 * 64; u += 256) {
        const int i = u >> 6;
        const int b = u & 63;          // fastest -> coalesced writes
        xT[(i0 + i) * 64 + b] = tile[i][b];
    }
}

// ---------------- Kernel 2: banded Gaussian FC ----------------
// grid = (NTILE=128, 2) = 256 blocks -> 1/CU (2 resident allowed for tail).
// block 256: cp = tid&31 -> cols (2cp, 2cp+1); g = tid>>5 -> rows (4g..4g+3).
// Inner loop per entry: 1 ds_read_b64 (w pair) + 1 ds_read_b128 (x quad, broadcast)
// + 8 FMA  => half the LDS issue rate of the R6 kernel.
__global__ __launch_bounds__(256, 2) void gauss_fc_kern(
    const float* __restrict__ x, const float* __restrict__ xT,
    const float4* __restrict__ mu4, const float4* __restrict__ sg4,
    const float* __restrict__ amp, const float* __restrict__ bias,
    float* __restrict__ out, const int use_xt) {

    __shared__ float4 list[PASS];        // {mu, kl, amp, idx_bits}  32 KB
    __shared__ float wtile[CH][64];      // weights per (entry, col) 16 KB
    __shared__ float xtile[CH][ROWS];    // x columns per (entry, row) 8 KB
    __shared__ int   cnt;

    const int tid = threadIdx.x;
    const int cc = (tid & 31) << 1;      // col-pair base: 0,2,...,62
    const int g4 = (tid >> 5) << 2;      // row-group base: 0,4,...,28
    const int tile0 = blockIdx.x * TQ;
    const int row0 = blockIdx.y * ROWS;
    const float lo = (float)tile0;
    const float hi = (float)(tile0 + TQ - 1);

    float acc0[4] = {0.f, 0.f, 0.f, 0.f};   // col cc,   rows g4..g4+3
    float acc1[4] = {0.f, 0.f, 0.f, 0.f};   // col cc+1, rows g4..g4+3

    for (int base = 0; base < IN_F; base += PASS) {
        if (tid == 0) cnt = 0;
        __syncthreads();

        // ---- float4 scan + LDS compaction ----
        const int q_end = (base + PASS) >> 2;
        for (int q = (base >> 2) + tid; q < q_end; q += 256) {
            const float4 m4 = mu4[q];
            const float4 s4 = sg4[q];
            const float ms[4] = {m4.x, m4.y, m4.z, m4.w};
            const float ss[4] = {s4.x, s4.y, s4.z, s4.w};
#pragma unroll
            for (int e = 0; e < 4; ++e) {
                const float m = ms[e];
                const float s = ss[e];
                // R = 5σ+1: dropped-tail absmax ~3e-5 << 0.3525 threshold
                const float R = 5.0f * fabsf(s) + 1.0f;
                if (m >= lo - R && m <= hi + R) {
                    const int i = (q << 2) + e;
                    const int p = atomicAdd(&cnt, 1);     // p < PASS guaranteed
                    // kl = -log2(e)/(2 s^2): w = a * exp2(kl * d^2)
                    list[p] = make_float4(m, -0.72134752f / (s * s), amp[i],
                                          __int_as_float(i));
                }
            }
        }
        __syncthreads();
        const int n = cnt;

        // ---- chunks: precompute weight tile + gather x tile, then pure-FMA loop ----
        for (int cb = 0; cb < n; cb += CH) {
            const int cn = min(CH, n - cb);

            // weight tile: cn*64 exps over 256 threads (exp2f -> single v_exp_f32)
            for (int u = tid; u < (cn << 6); u += 256) {
                const int j = u >> 6;
                const int col = u & 63;              // fastest -> conflict-free writes
                const float4 e = list[cb + j];
                const float d = (float)(tile0 + col) - e.x;
                wtile[j][col] = e.z * exp2f(e.y * d * d);
            }
            // x tile: 8 float4 per entry (32 rows), cn*8 float4 over 256 threads
            for (int u = tid; u < (cn << 3); u += 256) {
                const int ci = u >> 3;
                const int rq = (u & 7) << 2;
                const int i = __float_as_int(list[cb + ci].w);
                if (use_xt) {
                    *(float4*)&xtile[ci][rq] = *(const float4*)&xT[i * 64 + row0 + rq];
                } else {
                    xtile[ci][rq + 0] = x[(size_t)(row0 + rq + 0) * IN_F + i];
                    xtile[ci][rq + 1] = x[(size_t)(row0 + rq + 1) * IN_F + i];
                    xtile[ci][rq + 2] = x[(size_t)(row0 + rq + 2) * IN_F + i];
                    xtile[ci][rq + 3] = x[(size_t)(row0 + rq + 3) * IN_F + i];
                }
            }
            __syncthreads();

#pragma unroll 8
            for (int j = 0; j < cn; ++j) {
                const float2 wv = *(const float2*)&wtile[j][cc];   // ds_read_b64
                const float4 xv = *(const float4*)&xtile[j][g4];   // ds_read_b128 (bcast)
                acc0[0] += wv.x * xv.x;  acc1[0] += wv.y * xv.x;
                acc0[1] += wv.x * xv.y;  acc1[1] += wv.y * xv.y;
                acc0[2] += wv.x * xv.z;  acc1[2] += wv.y * xv.z;
                acc0[3] += wv.x * xv.w;  acc1[3] += wv.y * xv.w;
            }
            __syncthreads();
        }
    }

    // ---- epilogue: + bias, ReLU, contiguous float2 stores ----
    const float b0 = bias[tile0 + cc];
    const float b1 = bias[tile0 + cc + 1];
#pragma unroll
    for (int k = 0; k < 4; ++k) {
        float2 v = make_float2(fmaxf(acc0[k] + b0, 0.f), fmaxf(acc1[k] + b1, 0.f));
        *(float2*)&out[(size_t)(row0 + g4 + k) * OUT_F + tile0 + cc] = v;
    }
}

extern "C" void kernel_launch(void* const* d_in, const int* in_sizes, int n_in,
                              void* d_out, int out_size, void* d_ws, size_t ws_size,
                              hipStream_t stream) {
    const float* x     = (const float*)d_in[0];   // [64, 8192]
    const float* mu    = (const float*)d_in[1];   // [8192]
    const float* sigma = (const float*)d_in[2];   // [8192]
    const float* amp   = (const float*)d_in[3];   // [8192]
    const float* bias  = (const float*)d_in[4];   // [8192]
    float* out = (float*)d_out;

    const size_t xt_bytes = (size_t)IN_F * BATCH * sizeof(float);
    const int use_xt = (ws_size >= xt_bytes) ? 1 : 0;
    float* xT = (float*)d_ws;

    if (use_xt) {
        transpose_x_kern<<<IN_F / 64, 256, 0, stream>>>(x, xT);
    }
    dim3 grid(NTILE, BATCH / ROWS);
    gauss_fc_kern<<<grid, 256, 0, stream>>>(x, xT,
                                            (const float4*)mu, (const float4*)sigma,
                                            amp, bias, out, use_xt);
}